// Round 1
// 446.664 us; speedup vs baseline: 1.0054x; 1.0054x over previous
//
#include <hip/hip_runtime.h>
#include <hip/hip_bf16.h>
#include <stdint.h>

#define B_    64
#define S_    2048
#define ENC_  512
#define ATTN_ 256

typedef __bf16 bf16;
typedef bf16  bf16x8 __attribute__((ext_vector_type(8)));
typedef float f32x4  __attribute__((ext_vector_type(4)));

__device__ __forceinline__ float fexp2(float x) {
#if __has_builtin(__builtin_amdgcn_exp2f)
    return __builtin_amdgcn_exp2f(x);
#else
    return exp2f(x);
#endif
}
__device__ __forceinline__ float frcp(float x) {
#if __has_builtin(__builtin_amdgcn_rcpf)
    return __builtin_amdgcn_rcpf(x);
#else
    return 1.0f / x;
#endif
}
// tanh(x) = 1 - 2/(e^{2x}+1); overflow-safe (exp2->inf => 1, ->0 => -1)
__device__ __forceinline__ float fast_tanh(float x) {
    float e = fexp2(x * 2.8853900817779268f);
    return 1.0f - 2.0f * frcp(e + 1.0f);
}

__device__ __forceinline__ void async_copy16(const void* g, void* l) {
#if __has_builtin(__builtin_amdgcn_global_load_lds)
    __builtin_amdgcn_global_load_lds(
        (__attribute__((address_space(1))) void*)(g),
        (__attribute__((address_space(3))) void*)(l), 16, 0, 0);
#else
    *(uint4*)l = *(const uint4*)g;
#endif
}

// ---------------- setup: WT transpose->bf16 (blocks 0..511) + dec_proj (512..575)
// dec_proj blocks also zero ctx (needed for atomicAdd epilogue in k_ctx).
__global__ __launch_bounds__(256) void k_setup(const float* __restrict__ W_enc,
                                               const float* __restrict__ dec_state,
                                               const float* __restrict__ W_dec,
                                               bf16* __restrict__ WT,
                                               float* __restrict__ dp,
                                               float* __restrict__ ctx) {
    int blk = blockIdx.x;
    if (blk < 512) {
        int idx = blk * 256 + threadIdx.x;      // 0..131071
        int n = idx >> 9;                        // /512
        int k = idx & 511;
        WT[idx] = (bf16)W_enc[k * ATTN_ + n];    // coalesced writes
    } else {
        int b = blk - 512;
        int a = threadIdx.x;
        *(float2*)(ctx + b * 512 + a * 2) = make_float2(0.f, 0.f);
        const float* ds = dec_state + b * 512;
        float acc = 0.f;
#pragma unroll 8
        for (int d = 0; d < 512; ++d)
            acc += ds[d] * W_dec[d * ATTN_ + a];
        dp[b * ATTN_ + a] = acc;
    }
}

__device__ __forceinline__ void stage_b(const bf16* __restrict__ WT, bf16* bsbuf,
                                        int ks, int bcol4, int bslot, int tid) {
#pragma unroll
    for (int r = 0; r < 4; ++r) {
        int c = r * 64 + bcol4;
        int g = bslot ^ ((c + (c >> 2)) & 3);     // fetch swizzled chunk
        async_copy16(WT + (size_t)c * 512 + ks * 32 + g * 8,
                     bsbuf + r * 2048 + tid * 8);
    }
}

// ---------------- scores: GEMM(M=131072,K=512,N=256) + tanh.v epilogue ----
// v2: DOUBLE-BUFFERED LDS, ONE barrier per K-step. Next-step A loads (regs)
// and B global_load_lds are issued BEFORE the current step's MFMAs so HBM
// latency hides under compute; cvt+LDS-write lands after the MFMAs.
__global__ __launch_bounds__(256, 2) void k_scores(
    const float* __restrict__ enc,    // [131072][512]
    const bf16*  __restrict__ WT,     // [256][512] (n-major)
    const float* __restrict__ dp,     // [64][256]
    const float* __restrict__ v,      // [256]
    float* __restrict__ out_scores)   // [131072]
{
    __shared__ __align__(16) bf16 As[2][128 * 40];   // 2 x 10.0 KB, padded rows
    __shared__ __align__(16) bf16 Bs[2][256 * 32];   // 2 x 16.0 KB, swizzled chunks
    __shared__ float partial[4][64];

    const int tid  = threadIdx.x;
    const int wave = tid >> 6;
    const int lane = tid & 63;
    const int l15  = lane & 15;
    const int q    = lane >> 4;
    const int m0   = blockIdx.x * 128;
    const int b    = blockIdx.x >> 4;            // 16 blocks per batch

    const int mrow0 = (wave >> 1) * 64;
    const int ncol0 = (wave & 1) * 128;

    const f32x4 zero4 = {0.f, 0.f, 0.f, 0.f};
    f32x4 acc[4][8];
#pragma unroll
    for (int mt = 0; mt < 4; ++mt)
#pragma unroll
        for (int nt = 0; nt < 8; ++nt)
            acc[mt][nt] = zero4;

    // A staging: thread t -> row t>>1, k-half (t&1)*16 floats
    const int arow = tid >> 1;
    const int akc  = tid & 1;
    const float* ag = enc + (size_t)(m0 + arow) * 512 + akc * 16;
    const int aoff = arow * 40 + akc * 16;

    // B staging: round r -> col c = r*64 + (t>>2), chunk slot t&3
    const int bcol4 = tid >> 2;
    const int bslot = tid & 3;

    // ---- prologue: stage ks=0 into buffer 0 ----
    {
        float4 f0 = *(const float4*)(ag);
        float4 f1 = *(const float4*)(ag + 4);
        float4 f2 = *(const float4*)(ag + 8);
        float4 f3 = *(const float4*)(ag + 12);
        stage_b(WT, Bs[0], 0, bcol4, bslot, tid);
        bf16x8 lo, hi;
        lo[0]=(bf16)f0.x; lo[1]=(bf16)f0.y; lo[2]=(bf16)f0.z; lo[3]=(bf16)f0.w;
        lo[4]=(bf16)f1.x; lo[5]=(bf16)f1.y; lo[6]=(bf16)f1.z; lo[7]=(bf16)f1.w;
        hi[0]=(bf16)f2.x; hi[1]=(bf16)f2.y; hi[2]=(bf16)f2.z; hi[3]=(bf16)f2.w;
        hi[4]=(bf16)f3.x; hi[5]=(bf16)f3.y; hi[6]=(bf16)f3.z; hi[7]=(bf16)f3.w;
        *(bf16x8*)(&As[0][aoff])     = lo;
        *(bf16x8*)(&As[0][aoff + 8]) = hi;
    }
    __syncthreads();

    for (int ks = 0; ks < 16; ++ks) {
        const int cur = ks & 1;
        const bf16* Asc = As[cur];
        const bf16* Bsc = Bs[cur];

        // ---- fragments (current buffer) ----
        bf16x8 af[4];
#pragma unroll
        for (int mt = 0; mt < 4; ++mt) {
            int row = mrow0 + mt * 16 + l15;
            af[mt] = *(const bf16x8*)(Asc + row * 40 + q * 8);
        }
        bf16x8 bfr[8];
#pragma unroll
        for (int nt = 0; nt < 8; ++nt) {
            int col = ncol0 + nt * 16 + l15;
            int p = q ^ ((col + (col >> 2)) & 3);
            bfr[nt] = *(const bf16x8*)(Bsc + col * 32 + p * 8);
        }

        // ---- issue next-step loads BEFORE compute (latency cover) ----
        float4 f0, f1, f2, f3;
        if (ks < 15) {
            const float* s = ag + (ks + 1) * 32;
            f0 = *(const float4*)(s);
            f1 = *(const float4*)(s + 4);
            f2 = *(const float4*)(s + 8);
            f3 = *(const float4*)(s + 12);
            stage_b(WT, Bs[cur ^ 1], ks + 1, bcol4, bslot, tid);
        }

#pragma unroll
        for (int mt = 0; mt < 4; ++mt)
#pragma unroll
            for (int nt = 0; nt < 8; ++nt)
                acc[mt][nt] = __builtin_amdgcn_mfma_f32_16x16x32_bf16(af[mt], bfr[nt], acc[mt][nt], 0, 0, 0);

        // ---- convert + write next A tile (other buffer) ----
        if (ks < 15) {
            bf16x8 lo, hi;
            lo[0]=(bf16)f0.x; lo[1]=(bf16)f0.y; lo[2]=(bf16)f0.z; lo[3]=(bf16)f0.w;
            lo[4]=(bf16)f1.x; lo[5]=(bf16)f1.y; lo[6]=(bf16)f1.z; lo[7]=(bf16)f1.w;
            hi[0]=(bf16)f2.x; hi[1]=(bf16)f2.y; hi[2]=(bf16)f2.z; hi[3]=(bf16)f2.w;
            hi[4]=(bf16)f3.x; hi[5]=(bf16)f3.y; hi[6]=(bf16)f3.z; hi[7]=(bf16)f3.w;
            bf16* dst = &As[cur ^ 1][aoff];
            *(bf16x8*)(dst)     = lo;
            *(bf16x8*)(dst + 8) = hi;
        }
        __syncthreads();   // single barrier: publishes next buffer, retires reads
    }

    // ---- epilogue: scores[row] = sum_col tanh(C + dp[col]) * v[col] ----
    float dpv[8], vv[8];
#pragma unroll
    for (int nt = 0; nt < 8; ++nt) {
        int col = ncol0 + nt * 16 + l15;
        dpv[nt] = dp[b * 256 + col];
        vv[nt]  = v[col];
    }
#pragma unroll
    for (int mt = 0; mt < 4; ++mt) {
#pragma unroll
        for (int r = 0; r < 4; ++r) {
            float s = 0.f;
#pragma unroll
            for (int nt = 0; nt < 8; ++nt)
                s += fast_tanh(acc[mt][nt][r] + dpv[nt]) * vv[nt];
            s += __shfl_xor(s, 1, 16);
            s += __shfl_xor(s, 2, 16);
            s += __shfl_xor(s, 4, 16);
            s += __shfl_xor(s, 8, 16);
            if (l15 == 0)
                partial[wave][mt * 16 + q * 4 + r] = s;
        }
    }
    __syncthreads();
    if (tid < 128) {
        int mw   = tid >> 6;
        int rloc = tid & 63;
        out_scores[m0 + mw * 64 + rloc] =
            partial[mw * 2][rloc] + partial[mw * 2 + 1][rloc];
    }
}

// ---------------- fused softmax + context + reduce ------------------------
// grid = 64 b x 16 slabs (128 rows each). Every block redundantly computes
// the batch softmax stats from the 8KB score row (L2-hot), writes weights
// for its own slab, then streams its 256KB enc slab with 8-deep independent
// f32x4 loads and atomicAdd's its partial context into ctx (zeroed in setup).
__global__ __launch_bounds__(256) void k_ctx(const float* __restrict__ enc,
                                             const float* __restrict__ scores,
                                             float* __restrict__ attn,
                                             float* __restrict__ ctx) {
    __shared__ float red[256];
    __shared__ float wlds[128];
    __shared__ f32x4 vred[128];

    const int tid  = threadIdx.x;
    const int b    = blockIdx.x >> 4;
    const int slab = blockIdx.x & 15;
    const float* sc = scores + b * 2048;

    // ---- redundant softmax over the batch's 2048 scores ----
    float x[8];
    float mx = -1e30f;
#pragma unroll
    for (int i = 0; i < 8; ++i) { x[i] = sc[tid + 256 * i]; mx = fmaxf(mx, x[i]); }
    red[tid] = mx;
    __syncthreads();
    for (int off = 128; off > 0; off >>= 1) {
        if (tid < off) red[tid] = fmaxf(red[tid], red[tid + off]);
        __syncthreads();
    }
    mx = red[0];
    __syncthreads();

    float e[8];
    float lsum = 0.f;
#pragma unroll
    for (int i = 0; i < 8; ++i) { e[i] = fexp2((x[i] - mx) * 1.4426950408889634f); lsum += e[i]; }
    red[tid] = lsum;
    __syncthreads();
    for (int off = 128; off > 0; off >>= 1) {
        if (tid < off) red[tid] += red[tid + off];
        __syncthreads();
    }
    float inv = 1.0f / red[0];

    // weights for this block's slab: global + LDS copy for the context pass
#pragma unroll
    for (int i = 0; i < 8; ++i) {
        int idx = tid + 256 * i;
        int r   = idx - slab * 128;
        if ((unsigned)r < 128u) {
            float w = e[i] * inv;
            attn[b * 2048 + idx] = w;
            wlds[r] = w;
        }
    }
    __syncthreads();

    // ---- context partial over 128 rows, 8 loads in flight per thread ----
    const int eq = tid & 127;                 // e = eq*4 (float4)
    const int sr = tid >> 7;                  // 0/1 — wave-uniform
    const float* eb = enc + ((size_t)b * 2048 + slab * 128) * 512;

    f32x4 acc = {0.f, 0.f, 0.f, 0.f};
    for (int g = 0; g < 8; ++g) {
        const int sbase = g * 16 + sr * 8;
        f32x4 ev[8];
        float wv[8];
#pragma unroll
        for (int j = 0; j < 8; ++j) {
            ev[j] = *(const f32x4*)(eb + (size_t)(sbase + j) * 512 + eq * 4);
            wv[j] = wlds[sbase + j];
        }
#pragma unroll
        for (int j = 0; j < 8; ++j) acc += ev[j] * wv[j];
    }
    if (sr) vred[eq] = acc;
    __syncthreads();
    if (!sr) {
        acc += vred[eq];
        float* cp = ctx + b * 512 + eq * 4;
        atomicAdd(cp + 0, acc[0]);
        atomicAdd(cp + 1, acc[1]);
        atomicAdd(cp + 2, acc[2]);
        atomicAdd(cp + 3, acc[3]);
    }
}

extern "C" void kernel_launch(void* const* d_in, const int* in_sizes, int n_in,
                              void* d_out, int out_size, void* d_ws, size_t ws_size,
                              hipStream_t stream) {
    const float* enc       = (const float*)d_in[0];
    const float* dec_state = (const float*)d_in[1];
    const float* W_enc     = (const float*)d_in[2];
    const float* W_dec     = (const float*)d_in[3];
    const float* v         = (const float*)d_in[4];

    float* ctx  = (float*)d_out;                 // [64,512]
    float* attn = (float*)d_out + 64 * 512;      // [64,2048] weights

    // workspace: WT bf16 256KB | dp fp32 64KB | scores fp32 512KB
    char*  ws     = (char*)d_ws;
    bf16*  WT     = (bf16*)ws;
    float* dp     = (float*)(ws + 256 * 1024);
    float* scores = (float*)(ws + 256 * 1024 + 64 * 1024);

    k_setup <<<576, 256, 0, stream>>>(W_enc, dec_state, W_dec, WT, dp, ctx);
    k_scores<<<1024, 256, 0, stream>>>(enc, WT, dp, v, scores);
    k_ctx   <<<1024, 256, 0, stream>>>(enc, scores, attn, ctx);
}